// Round 2
// baseline (625.569 us; speedup 1.0000x reference)
//
#include <hip/hip_runtime.h>
#include <cstdint>

// B=32, T=2048, D=1024.  scores[b,t] = v · relu(W_h·hidden[b] + W_e·enc[b,t] + bias)
// out = softmax_T(scores).
// R2 structure: one block per 128-row M-tile; loop all 8 N-tiles inside the block
// (A-slice stays L2/L3-hot, scores accumulate in registers -> no atomics).
// Pass 0 fuses fp32->bf16 conversion of A (persisted to ws for passes 1-7).
// LDS k-group XOR swizzle kills the 8-way ds_read_b128 bank conflicts.

#define GLOBAL_AS __attribute__((address_space(1)))
#define LDS_AS    __attribute__((address_space(3)))

typedef __bf16 bf16x8 __attribute__((ext_vector_type(8)));
typedef float  f32x4  __attribute__((ext_vector_type(4)));

__device__ __forceinline__ unsigned int f2bf(float x) {
    unsigned int u = __builtin_bit_cast(unsigned int, x);
    u += 0x7fffu + ((u >> 16) & 1u);   // RNE
    return u >> 16;
}

__device__ __forceinline__ uint4 pack8(float4 f0, float4 f1) {
    uint4 o;
    o.x = f2bf(f0.x) | (f2bf(f0.y) << 16);
    o.y = f2bf(f0.z) | (f2bf(f0.w) << 16);
    o.z = f2bf(f1.x) | (f2bf(f1.y) << 16);
    o.w = f2bf(f1.z) | (f2bf(f1.w) << 16);
    return o;
}

// ---- W_e = W[:,1024:2048] fp32 -> bf16 [1024 x 1024], k contiguous ----
__global__ __launch_bounds__(256) void k_convert_we(const float* __restrict__ W,
                                                    uint2* __restrict__ out) {
    int idx = blockIdx.x * 256 + threadIdx.x;
    int i = idx * 4;
    int n = i >> 10, k = i & 1023;
    const float4 f = *(const float4*)(W + (size_t)n * 2048 + 1024 + k);
    uint2 o;
    o.x = f2bf(f.x) | (f2bf(f.y) << 16);
    o.y = f2bf(f.z) | (f2bf(f.w) << 16);
    out[idx] = o;
}

// ---- u[b,d] = hidden[b,:]·W[d,0:1024] + bias[d] ; one block per d, split-K ----
__global__ __launch_bounds__(256) void k_hidden_proj(const float* __restrict__ hidden,
                                                     const float* __restrict__ W,
                                                     const float* __restrict__ bias,
                                                     float* __restrict__ u) {
    __shared__ float wrow[1024];
    __shared__ float red[256];
    const int tid = threadIdx.x, d = blockIdx.x;
    ((float4*)wrow)[tid] = ((const float4*)(W + (size_t)d * 2048))[tid];  // coalesced 4KB stage
    __syncthreads();
    const int b = tid & 31, kc = tid >> 5;       // 32 batches x 8 k-chunks of 128
    const float* h = hidden + b * 1024 + kc * 128;
    const float* w = wrow + kc * 128;
    float acc = 0.f;
    #pragma unroll 8
    for (int i = 0; i < 128; i += 4) {
        float4 hv = *(const float4*)(h + i);
        acc += w[i] * hv.x + w[i + 1] * hv.y + w[i + 2] * hv.z + w[i + 3] * hv.w;
    }
    red[tid] = acc;
    __syncthreads();
    if (tid < 32) {
        float s = 0.f;
        #pragma unroll
        for (int j = 0; j < 8; j++) s += red[j * 32 + tid];
        u[tid * 1024 + d] = s + bias[d];
    }
}

// ---- fused GEMM + relu·v score: block = 128 rows, loops all N, converts A on pass 0 ----
__global__ __launch_bounds__(256) void k_gemm_score(
        const float* __restrict__ Af,            // enc fp32 [65536,1024]
        unsigned short* __restrict__ Ab,         // enc bf16 ws [65536,1024]
        const unsigned short* __restrict__ Bw,   // W_e bf16 [1024,1024]
        const float* __restrict__ u,             // [32,1024] (incl. bias)
        const float* __restrict__ v,             // [1024]
        float* __restrict__ scores) {            // [65536]
    constexpr int K = 1024, BK = 32;
    __shared__ __align__(16) unsigned short As[128 * BK];  // 8 KB
    __shared__ __align__(16) unsigned short Bs[128 * BK];  // 8 KB
    __shared__ float red[2][128];

    const int tid  = threadIdx.x;
    const int wave = tid >> 6;
    const int lane = tid & 63;
    const int mb   = blockIdx.x;                 // 0..511
    const int wm = wave & 1, wn = wave >> 1;     // 2x2 waves over 128x128
    const int q = lane >> 4, cl = lane & 15;

    // fragment LDS offsets (shorts); XOR swizzle (row>>1)&3 -> 2-way (free) banks
    int aoff[4], boff[4];
    #pragma unroll
    for (int i = 0; i < 4; i++) {
        int ra = wm * 64 + i * 16 + cl;
        aoff[i] = ra * BK + (q ^ ((ra >> 1) & 3)) * 8;
        int rb = wn * 64 + i * 16 + cl;
        boff[i] = rb * BK + (q ^ ((rb >> 1) & 3)) * 8;
    }

    // staging geometry: chunk = wave*2+c = 16 rows x 32k; lane -> (row, k-slot)
    const int rl  = lane >> 2;
    const int kbs = lane & 3;
    int srow[2], skb[2];
    #pragma unroll
    for (int c = 0; c < 2; c++) {
        int chunk = wave * 2 + c;
        srow[c] = chunk * 16 + rl;
        skb[c]  = kbs ^ ((srow[c] >> 1) & 3);    // data k-group stored in this linear slot
    }

    float sacc[4][4];
    #pragma unroll
    for (int i = 0; i < 4; i++)
        #pragma unroll
        for (int r = 0; r < 4; r++) sacc[i][r] = 0.f;

    const int bidx = mb >> 4;   // batch of these 128 rows
    f32x4 acc[4][4];

    for (int nb = 0; nb < 8; nb++) {
        #pragma unroll
        for (int i = 0; i < 4; i++)
            #pragma unroll
            for (int j = 0; j < 4; j++) acc[i][j] = (f32x4){0.f, 0.f, 0.f, 0.f};

        for (int k0 = 0; k0 < K; k0 += BK) {
            if (nb == 0) {
                // A: fp32 load -> bf16 pack -> LDS (ds_write_b128) + persist to Ab
                #pragma unroll
                for (int c = 0; c < 2; c++) {
                    const int chunk = wave * 2 + c;
                    const size_t aidx = (size_t)(mb * 128 + srow[c]) * K + k0 + skb[c] * 8;
                    const float4* gs = (const float4*)(Af + aidx);
                    uint4 o = pack8(gs[0], gs[1]);
                    *(uint4*)(As + chunk * 512 + lane * 8) = o;
                    *(uint4*)(Ab + aidx) = o;
                    const unsigned short* gb = Bw + (size_t)srow[c] * K + k0 + skb[c] * 8;
                    __builtin_amdgcn_global_load_lds((GLOBAL_AS void*)(size_t)gb,
                                                     (LDS_AS void*)(Bs + chunk * 512), 16, 0, 0);
                }
            } else {
                #pragma unroll
                for (int c = 0; c < 2; c++) {
                    const int chunk = wave * 2 + c;
                    const unsigned short* ga = Ab + (size_t)(mb * 128 + srow[c]) * K + k0 + skb[c] * 8;
                    const unsigned short* gb = Bw + (size_t)(nb * 128 + srow[c]) * K + k0 + skb[c] * 8;
                    __builtin_amdgcn_global_load_lds((GLOBAL_AS void*)(size_t)ga,
                                                     (LDS_AS void*)(As + chunk * 512), 16, 0, 0);
                    __builtin_amdgcn_global_load_lds((GLOBAL_AS void*)(size_t)gb,
                                                     (LDS_AS void*)(Bs + chunk * 512), 16, 0, 0);
                }
            }
            __syncthreads();
            bf16x8 afr[4], bfr[4];
            #pragma unroll
            for (int i = 0; i < 4; i++) afr[i] = *(const bf16x8*)(As + aoff[i]);
            #pragma unroll
            for (int j = 0; j < 4; j++) bfr[j] = *(const bf16x8*)(Bs + boff[j]);
            #pragma unroll
            for (int i = 0; i < 4; i++)
                #pragma unroll
                for (int j = 0; j < 4; j++)
                    acc[i][j] = __builtin_amdgcn_mfma_f32_16x16x32_bf16(afr[i], bfr[j], acc[i][j], 0, 0, 0);
            __syncthreads();
        }

        // per-pass epilogue: sacc += relu(E + u) · v over this pass's 128 n's
        float vv[4], uu[4];
        #pragma unroll
        for (int j = 0; j < 4; j++) {
            int n = nb * 128 + wn * 64 + j * 16 + cl;
            vv[j] = v[n];
            uu[j] = u[bidx * 1024 + n];
        }
        #pragma unroll
        for (int i = 0; i < 4; i++)
            #pragma unroll
            for (int r = 0; r < 4; r++) {
                float s = sacc[i][r];
                #pragma unroll
                for (int j = 0; j < 4; j++)
                    s += fmaxf(acc[i][j][r] + uu[j], 0.f) * vv[j];
                sacc[i][r] = s;
            }
    }

    // final reduce: 16 cl-lanes (shfl) then 2 wn-waves (LDS); direct store, no atomics
    #pragma unroll
    for (int i = 0; i < 4; i++)
        #pragma unroll
        for (int r = 0; r < 4; r++) {
            float s = sacc[i][r];
            s += __shfl_xor(s, 1);
            s += __shfl_xor(s, 2);
            s += __shfl_xor(s, 4);
            s += __shfl_xor(s, 8);
            if (cl == 0) red[wn][wm * 64 + i * 16 + q * 4 + r] = s;
        }
    __syncthreads();
    if (tid < 128) scores[mb * 128 + tid] = red[0][tid] + red[1][tid];
}

// ---- softmax over T=2048 per batch ----
__global__ __launch_bounds__(256) void k_softmax(const float* __restrict__ scores,
                                                 float* __restrict__ out) {
    __shared__ float red[4];
    int b = blockIdx.x;
    int t0 = threadIdx.x;
    int wave = threadIdx.x >> 6, lane = threadIdx.x & 63;
    const float* s = scores + b * 2048;
    float vals[8];
    float lmax = -1e30f;
    #pragma unroll
    for (int i = 0; i < 8; i++) {
        vals[i] = s[t0 + i * 256];
        lmax = fmaxf(lmax, vals[i]);
    }
    for (int o = 32; o > 0; o >>= 1) lmax = fmaxf(lmax, __shfl_xor(lmax, o));
    if (lane == 0) red[wave] = lmax;
    __syncthreads();
    float gmax = fmaxf(fmaxf(red[0], red[1]), fmaxf(red[2], red[3]));
    float lsum = 0.f;
    #pragma unroll
    for (int i = 0; i < 8; i++) {
        vals[i] = expf(vals[i] - gmax);
        lsum += vals[i];
    }
    for (int o = 32; o > 0; o >>= 1) lsum += __shfl_xor(lsum, o);
    __syncthreads();
    if (lane == 0) red[wave] = lsum;
    __syncthreads();
    float inv = 1.0f / (red[0] + red[1] + red[2] + red[3]);
    #pragma unroll
    for (int i = 0; i < 8; i++) out[b * 2048 + t0 + i * 256] = vals[i] * inv;
}

extern "C" void kernel_launch(void* const* d_in, const int* in_sizes, int n_in,
                              void* d_out, int out_size, void* d_ws, size_t ws_size,
                              hipStream_t stream) {
    const float* hidden = (const float*)d_in[0];  // [32,1024]
    const float* enc    = (const float*)d_in[1];  // [32,2048,1024]
    const float* W      = (const float*)d_in[2];  // [1024,2048]
    const float* bias   = (const float*)d_in[3];  // [1024]
    const float* v      = (const float*)d_in[4];  // [1024]
    float* out = (float*)d_out;                   // [32,1,2048]

    char* ws = (char*)d_ws;
    unsigned short* encb = (unsigned short*)ws;                       // 128 MB bf16 A
    unsigned short* Web  = (unsigned short*)(ws + 134217728);         // 2 MB bf16 W_e
    float* u      = (float*)(ws + 134217728 + 2097152);               // 128 KB
    float* scores = (float*)(ws + 134217728 + 2097152 + 131072);      // 256 KB

    k_hidden_proj<<<1024, 256, 0, stream>>>(hidden, W, bias, u);
    k_convert_we<<<1024, 256, 0, stream>>>(W, (uint2*)Web);
    k_gemm_score<<<512, 256, 0, stream>>>(enc, encb, Web, u, v, scores);
    k_softmax<<<32, 256, 0, stream>>>(scores, out);
}

// Round 3
// 559.461 us; speedup vs baseline: 1.1182x; 1.1182x over previous
//
#include <hip/hip_runtime.h>
#include <cstdint>

// B=32, T=2048, D=1024.  scores[b,t] = v · relu(W_h·hidden[b] + W_e·enc[b,t] + bias)
// out = softmax_T(scores).
// R3: convert kernel (fp32->bf16 A) + GEMM with grid (512 mb, 2 z): each block does
// 4 serial nb-passes over a 128-row M-tile (reg-resident score accumulation, no
// atomics); 4 blocks/CU occupancy; BK=64 (halved barrier count); 8-granule XOR
// swizzle keeps LDS bank conflicts at 0. scores2[2][65536], softmax sums halves.

#define GLOBAL_AS __attribute__((address_space(1)))
#define LDS_AS    __attribute__((address_space(3)))

typedef __bf16 bf16x8 __attribute__((ext_vector_type(8)));
typedef float  f32x4  __attribute__((ext_vector_type(4)));

__device__ __forceinline__ unsigned int f2bf(float x) {
    unsigned int u = __builtin_bit_cast(unsigned int, x);
    u += 0x7fffu + ((u >> 16) & 1u);   // RNE
    return u >> 16;
}

// ---- enc fp32 -> bf16, 8 elems/thread, pure streaming ----
__global__ __launch_bounds__(256) void k_convert_enc(const float4* __restrict__ in,
                                                     uint4* __restrict__ out) {
    size_t idx = (size_t)blockIdx.x * 256 + threadIdx.x;
    float4 f0 = in[idx * 2];
    float4 f1 = in[idx * 2 + 1];
    uint4 o;
    o.x = f2bf(f0.x) | (f2bf(f0.y) << 16);
    o.y = f2bf(f0.z) | (f2bf(f0.w) << 16);
    o.z = f2bf(f1.x) | (f2bf(f1.y) << 16);
    o.w = f2bf(f1.z) | (f2bf(f1.w) << 16);
    out[idx] = o;
}

// ---- W_e = W[:,1024:2048] fp32 -> bf16 [1024 x 1024], k contiguous ----
__global__ __launch_bounds__(256) void k_convert_we(const float* __restrict__ W,
                                                    uint2* __restrict__ out) {
    int idx = blockIdx.x * 256 + threadIdx.x;
    int i = idx * 4;
    int n = i >> 10, k = i & 1023;
    const float4 f = *(const float4*)(W + (size_t)n * 2048 + 1024 + k);
    uint2 o;
    o.x = f2bf(f.x) | (f2bf(f.y) << 16);
    o.y = f2bf(f.z) | (f2bf(f.w) << 16);
    out[idx] = o;
}

// ---- u[b,d] = hidden[b,:]·W[d,0:1024] + bias[d] ; one block per d, split-K ----
__global__ __launch_bounds__(256) void k_hidden_proj(const float* __restrict__ hidden,
                                                     const float* __restrict__ W,
                                                     const float* __restrict__ bias,
                                                     float* __restrict__ u) {
    __shared__ float wrow[1024];
    __shared__ float red[256];
    const int tid = threadIdx.x, d = blockIdx.x;
    ((float4*)wrow)[tid] = ((const float4*)(W + (size_t)d * 2048))[tid];
    __syncthreads();
    const int b = tid & 31, kc = tid >> 5;
    const float* h = hidden + b * 1024 + kc * 128;
    const float* w = wrow + kc * 128;
    float acc = 0.f;
    #pragma unroll 8
    for (int i = 0; i < 128; i += 4) {
        float4 hv = *(const float4*)(h + i);
        acc += w[i] * hv.x + w[i + 1] * hv.y + w[i + 2] * hv.z + w[i + 3] * hv.w;
    }
    red[tid] = acc;
    __syncthreads();
    if (tid < 32) {
        float s = 0.f;
        #pragma unroll
        for (int j = 0; j < 8; j++) s += red[j * 32 + tid];
        u[tid * 1024 + d] = s + bias[d];
    }
}

// ---- GEMM + fused relu·v score. grid (512, 2): block = 128-row M-tile, 4 nb-passes ----
__global__ __launch_bounds__(256, 4) void k_gemm_score(
        const unsigned short* __restrict__ Ab,   // enc bf16 [65536,1024]
        const unsigned short* __restrict__ Bw,   // W_e bf16 [1024,1024]
        const float* __restrict__ u,             // [32,1024] (incl. bias)
        const float* __restrict__ v,             // [1024]
        float* __restrict__ scores2) {           // [2,65536]
    constexpr int K = 1024, BK = 64;
    __shared__ __align__(16) unsigned short As[128 * BK];  // 16 KB
    __shared__ __align__(16) unsigned short Bs[128 * BK];  // 16 KB
    __shared__ float red[2][128];

    const int tid  = threadIdx.x;
    const int wave = tid >> 6;
    const int lane = tid & 63;
    const int mb   = blockIdx.x;       // 0..511
    const int z    = blockIdx.y;       // 0..1 (nb half); z-pair of an mb shares XCD
    const int wm = wave & 1, wn = wave >> 1;
    const int q = lane >> 4, cl = lane & 15;

    // fragment LDS offsets (shorts) for k-half h=0; h=1 is ^32 (granule^4).
    // row r, global k-granule G in [0,8): offset = r*64 + (G ^ (r&7))*8
    int aoff[4], boff[4];
    #pragma unroll
    for (int i = 0; i < 4; i++) {
        int ra = wm * 64 + i * 16 + cl;
        aoff[i] = ra * 64 + ((q ^ (ra & 7)) << 3);
        int rb = wn * 64 + i * 16 + cl;
        boff[i] = rb * 64 + ((q ^ (rb & 7)) << 3);
    }

    // staging: 16 chunks of 1KB per matrix; wave does chunks wave*4+c
    // lane -> row = chunk*8 + (lane>>3), linear slot = lane&7, fetch granule = slot ^ (row&7)
    int soff[4];   // element offset within [128 x K] source for (row, granule)
    #pragma unroll
    for (int c = 0; c < 4; c++) {
        int row = (wave * 4 + c) * 8 + (lane >> 3);
        int g   = (lane & 7) ^ (row & 7);
        soff[c] = row * K + g * 8;
    }
    const unsigned short* Abase = Ab + (size_t)(mb * 128) * K;

    float sacc[4][4];
    #pragma unroll
    for (int i = 0; i < 4; i++)
        #pragma unroll
        for (int r = 0; r < 4; r++) sacc[i][r] = 0.f;

    const int bidx = mb >> 4;
    f32x4 acc[4][4];

    for (int p = 0; p < 4; p++) {
        const int nb = z * 4 + p;
        const unsigned short* Bbase = Bw + (size_t)(nb * 128) * K;
        #pragma unroll
        for (int i = 0; i < 4; i++)
            #pragma unroll
            for (int j = 0; j < 4; j++) acc[i][j] = (f32x4){0.f, 0.f, 0.f, 0.f};

        for (int k0 = 0; k0 < K; k0 += BK) {
            #pragma unroll
            for (int c = 0; c < 4; c++) {
                const int chunk = wave * 4 + c;
                __builtin_amdgcn_global_load_lds(
                    (GLOBAL_AS void*)(size_t)(Abase + soff[c] + k0),
                    (LDS_AS void*)(As + chunk * 512), 16, 0, 0);
                __builtin_amdgcn_global_load_lds(
                    (GLOBAL_AS void*)(size_t)(Bbase + soff[c] + k0),
                    (LDS_AS void*)(Bs + chunk * 512), 16, 0, 0);
            }
            __syncthreads();
            #pragma unroll
            for (int h = 0; h < 2; h++) {
                const int hx = h * 32;   // granule^4 == short-offset^32 (no carry)
                bf16x8 afr[4], bfr[4];
                #pragma unroll
                for (int i = 0; i < 4; i++) afr[i] = *(const bf16x8*)(As + (aoff[i] ^ hx));
                #pragma unroll
                for (int j = 0; j < 4; j++) bfr[j] = *(const bf16x8*)(Bs + (boff[j] ^ hx));
                #pragma unroll
                for (int i = 0; i < 4; i++)
                    #pragma unroll
                    for (int j = 0; j < 4; j++)
                        acc[i][j] = __builtin_amdgcn_mfma_f32_16x16x32_bf16(afr[i], bfr[j], acc[i][j], 0, 0, 0);
            }
            __syncthreads();
        }

        // fold this pass's 128 n's into sacc: += relu(E + u) · v
        float vv[4], uu[4];
        #pragma unroll
        for (int j = 0; j < 4; j++) {
            int n = nb * 128 + wn * 64 + j * 16 + cl;
            vv[j] = v[n];
            uu[j] = u[bidx * 1024 + n];
        }
        #pragma unroll
        for (int i = 0; i < 4; i++)
            #pragma unroll
            for (int r = 0; r < 4; r++) {
                float s = sacc[i][r];
                #pragma unroll
                for (int j = 0; j < 4; j++)
                    s += fmaxf(acc[i][j][r] + uu[j], 0.f) * vv[j];
                sacc[i][r] = s;
            }
    }

    // reduce 16 cl-lanes (shfl) then 2 wn-waves (LDS); direct store per z-half
    #pragma unroll
    for (int i = 0; i < 4; i++)
        #pragma unroll
        for (int r = 0; r < 4; r++) {
            float s = sacc[i][r];
            s += __shfl_xor(s, 1);
            s += __shfl_xor(s, 2);
            s += __shfl_xor(s, 4);
            s += __shfl_xor(s, 8);
            if (cl == 0) red[wn][wm * 64 + i * 16 + q * 4 + r] = s;
        }
    __syncthreads();
    if (tid < 128) scores2[(size_t)z * 65536 + mb * 128 + tid] = red[0][tid] + red[1][tid];
}

// ---- softmax over T=2048 per batch; sums the two z-halves ----
__global__ __launch_bounds__(256) void k_softmax(const float* __restrict__ scores2,
                                                 float* __restrict__ out) {
    __shared__ float red[4];
    int b = blockIdx.x;
    int t0 = threadIdx.x;
    int wave = threadIdx.x >> 6, lane = threadIdx.x & 63;
    const float* s0 = scores2 + b * 2048;
    const float* s1 = scores2 + 65536 + b * 2048;
    float vals[8];
    float lmax = -1e30f;
    #pragma unroll
    for (int i = 0; i < 8; i++) {
        int t = t0 + i * 256;
        vals[i] = s0[t] + s1[t];
        lmax = fmaxf(lmax, vals[i]);
    }
    for (int o = 32; o > 0; o >>= 1) lmax = fmaxf(lmax, __shfl_xor(lmax, o));
    if (lane == 0) red[wave] = lmax;
    __syncthreads();
    float gmax = fmaxf(fmaxf(red[0], red[1]), fmaxf(red[2], red[3]));
    float lsum = 0.f;
    #pragma unroll
    for (int i = 0; i < 8; i++) {
        vals[i] = expf(vals[i] - gmax);
        lsum += vals[i];
    }
    for (int o = 32; o > 0; o >>= 1) lsum += __shfl_xor(lsum, o);
    __syncthreads();
    if (lane == 0) red[wave] = lsum;
    __syncthreads();
    float inv = 1.0f / (red[0] + red[1] + red[2] + red[3]);
    #pragma unroll
    for (int i = 0; i < 8; i++) out[b * 2048 + t0 + i * 256] = vals[i] * inv;
}

extern "C" void kernel_launch(void* const* d_in, const int* in_sizes, int n_in,
                              void* d_out, int out_size, void* d_ws, size_t ws_size,
                              hipStream_t stream) {
    const float* hidden = (const float*)d_in[0];  // [32,1024]
    const float* enc    = (const float*)d_in[1];  // [32,2048,1024]
    const float* W      = (const float*)d_in[2];  // [1024,2048]
    const float* bias   = (const float*)d_in[3];  // [1024]
    const float* v      = (const float*)d_in[4];  // [1024]
    float* out = (float*)d_out;                   // [32,1,2048]

    char* ws = (char*)d_ws;
    unsigned short* encb = (unsigned short*)ws;                       // 128 MB bf16 A
    unsigned short* Web  = (unsigned short*)(ws + 134217728);         // 2 MB bf16 W_e
    float* u       = (float*)(ws + 134217728 + 2097152);              // 128 KB
    float* scores2 = (float*)(ws + 134217728 + 2097152 + 131072);     // 512 KB

    k_convert_enc<<<32768, 256, 0, stream>>>((const float4*)enc, (uint4*)encb);
    k_convert_we<<<1024, 256, 0, stream>>>(W, (uint2*)Web);
    k_hidden_proj<<<1024, 256, 0, stream>>>(hidden, W, bias, u);
    dim3 g(512, 2);
    k_gemm_score<<<g, 256, 0, stream>>>(encb, Web, u, v, scores2);
    k_softmax<<<32, 256, 0, stream>>>(scores2, out);
}